// Round 1
// 1356.423 us; speedup vs baseline: 1.0728x; 1.0728x over previous
//
#include <hip/hip_runtime.h>
#include <hip/hip_bf16.h>

#define EMB 512
#define HID 512
#define UNITS 512
#define BS 1024
#define SEQ 360

typedef __attribute__((ext_vector_type(4))) float f32x4;
typedef __attribute__((ext_vector_type(8))) short bf16x8;

__device__ __forceinline__ unsigned int pk2bf(float lo, float hi) {
    unsigned int ulo = __float_as_uint(lo);
    unsigned int uhi = __float_as_uint(hi);
    ulo += 0x7fffu + ((ulo >> 16) & 1u);   // rne
    uhi += 0x7fffu + ((uhi >> 16) & 1u);
    return (ulo >> 16) | (uhi & 0xffff0000u);
}

// ---------------- Kernel 0: W1 fp32 -> bf16, wave-coalesced fragment layout ----
// Packed layout (uint4 granularity, 8 bf16 elems each):
//   idx16 = ((u>>4)*16 + (e>>5))*64 + (u&15)*4 + ((e>>3)&3)
// so a wave's bfrag load (col=lane&15, quad=lane>>4) for one 16-unit group and one
// 32-wide K chunk is a contiguous, aligned 1KB region.
__global__ __launch_bounds__(256) void k_convert_w1(const float* __restrict__ w1,
                                                    unsigned short* __restrict__ w1p) {
    int t = blockIdx.x * 256 + threadIdx.x;   // 32768 threads total
    int u = t >> 6;          // 0..511 unit
    int eg = t & 63;         // 8-elem group
    int e = eg << 3;
    const float4* src = (const float4*)(w1 + (size_t)u * 512 + e);
    float4 v0 = src[0], v1 = src[1];
    uint4 o;
    o.x = pk2bf(v0.x, v0.y);
    o.y = pk2bf(v0.z, v0.w);
    o.z = pk2bf(v1.x, v1.y);
    o.w = pk2bf(v1.z, v1.w);
    int g = u >> 4, col = u & 15;
    int c = e >> 5, quad = (e >> 3) & 3;
    ((uint4*)w1p)[((size_t)(g * 16 + c) * 64) + col * 4 + quad] = o;
}

// ---------------- Kernel 1: h_proj = relu(hidden @ W2^T + b2) ----------------
__global__ __launch_bounds__(256) void k_hproj(const float* __restrict__ hidden,
                                               const float* __restrict__ w2,
                                               const float* __restrict__ b2,
                                               float* __restrict__ hp) {
    __shared__ float hid[4 * 512];
    int t = threadIdx.x;
    int b0 = blockIdx.x * 4;
    const float4* src = (const float4*)(hidden + (size_t)b0 * 512);
    ((float4*)hid)[t * 2] = src[t * 2];
    ((float4*)hid)[t * 2 + 1] = src[t * 2 + 1];
    __syncthreads();
    int u0 = t, u1 = t + 256;
    float acc0[4] = {0.f, 0.f, 0.f, 0.f};
    float acc1[4] = {0.f, 0.f, 0.f, 0.f};
    const float4* w2_0 = (const float4*)(w2 + (size_t)u0 * 512);
    const float4* w2_1 = (const float4*)(w2 + (size_t)u1 * 512);
    const float4* h4 = (const float4*)hid;
    for (int k = 0; k < 128; ++k) {
        float4 a = w2_0[k];
        float4 c = w2_1[k];
#pragma unroll
        for (int bb = 0; bb < 4; ++bb) {
            float4 hv = h4[bb * 128 + k];
            acc0[bb] += a.x * hv.x + a.y * hv.y + a.z * hv.z + a.w * hv.w;
            acc1[bb] += c.x * hv.x + c.y * hv.y + c.z * hv.z + c.w * hv.w;
        }
    }
    float bias0 = b2[u0], bias1 = b2[u1];
#pragma unroll
    for (int bb = 0; bb < 4; ++bb) {
        hp[(size_t)(b0 + bb) * 512 + u0] = fmaxf(acc0[bb] + bias0, 0.f);
        hp[(size_t)(b0 + bb) * 512 + u1] = fmaxf(acc1[bb] + bias1, 0.f);
    }
}

// ---------------- Kernel 2: fused scores ----------------
// Block = 64 seq-rows x 256 units (half of UNITS). 4 waves, each 64x64 -> acc[4][4]
// (64 f32/lane instead of 128 -> target 3 waves/SIMD). Two half-blocks per
// (b, tile) write partial tanh-sums; k_softctx adds them.
#define MT 64
#define KT 64

__global__ __launch_bounds__(256, 3) void k_score(const float* __restrict__ F,
                                                  const unsigned short* __restrict__ W1p,
                                                  const float* __restrict__ b1,
                                                  const float* __restrict__ hp,
                                                  const float* __restrict__ Vw,
                                                  float* __restrict__ scoresP) {
    // A tile: 64 rows x 64 bf16, 8 chunks of 16B per row, XOR-swizzled
    __shared__ uint4 lsA[MT * 8];          // 8 KB
    __shared__ float lds_part[4][MT];

    int t = threadIdx.x;
    int wave = t >> 6, lane = t & 63;
    int col = lane & 15, quad = lane >> 4;
    int half = blockIdx.x & 1;
    int tb = blockIdx.x >> 1;
    int tile = tb % 6;
    int b = tb / 6;
    int s0 = tile * MT;

    f32x4 acc[4][4];
#pragma unroll
    for (int mb = 0; mb < 4; ++mb)
#pragma unroll
        for (int nb = 0; nb < 4; ++nb) {
            f32x4 z = {0.f, 0.f, 0.f, 0.f};
            acc[mb][nb] = z;
        }

    // staging map: 4 threads per row, each loads 16 consecutive floats
    int srow = t >> 2;              // 0..63
    int kpi = t & 3;                // 16-float column group
    int sIdx = s0 + srow;
    if (sIdx > 359) sIdx = 359;     // clamp; writes masked
    const float* Fr = F + ((size_t)(b * 360 + sIdx) * 512 + kpi * 16);
    int sw = srow & 7;
    int c0 = (2 * kpi) ^ sw;        // swizzled chunk indices
    int c1 = (2 * kpi + 1) ^ sw;
    uint4* wdst0 = &lsA[srow * 8 + c0];
    uint4* wdst1 = &lsA[srow * 8 + c1];

    int ugrp0 = half * 16 + wave * 4;          // 16-unit group base for this wave
    const unsigned short* Bbase = W1p + (size_t)ugrp0 * 8192 + (size_t)(col * 4 + quad) * 8;
    int cw = col & 7;

    // prologue prefetch (k0 = 0)
    float4 a0 = *(const float4*)(Fr);
    float4 a1 = *(const float4*)(Fr + 4);
    float4 a2 = *(const float4*)(Fr + 8);
    float4 a3 = *(const float4*)(Fr + 12);

#pragma unroll
    for (int k0 = 0; k0 < 512; k0 += KT) {
        // pack current tile (registers only, before barrier)
        uint4 u0, u1;
        u0.x = pk2bf(a0.x, a0.y); u0.y = pk2bf(a0.z, a0.w);
        u0.z = pk2bf(a1.x, a1.y); u0.w = pk2bf(a1.z, a1.w);
        u1.x = pk2bf(a2.x, a2.y); u1.y = pk2bf(a2.z, a2.w);
        u1.z = pk2bf(a3.x, a3.y); u1.w = pk2bf(a3.z, a3.w);
        __syncthreads();            // all reads of previous tile done
        *wdst0 = u0;
        *wdst1 = u1;
        // prefetch next A tile into registers (overlaps MFMA below)
        float4 n0 = {0.f,0.f,0.f,0.f}, n1 = n0, n2 = n0, n3 = n0;
        if (k0 + KT < 512) {
            const float* Fn = Fr + k0 + KT;
            n0 = *(const float4*)(Fn);
            n1 = *(const float4*)(Fn + 4);
            n2 = *(const float4*)(Fn + 8);
            n3 = *(const float4*)(Fn + 12);
        }
        __syncthreads();            // staging visible
#pragma unroll
        for (int kk = 0; kk < KT; kk += 32) {
            int kkc = kk >> 3;      // chunk base within tile (0 or 4)
            const unsigned short* Bk = Bbase + (size_t)(k0 + kk) * 16;
            bf16x8 bfrag[4];
#pragma unroll
            for (int nb = 0; nb < 4; ++nb)
                bfrag[nb] = *(const bf16x8*)(Bk + (size_t)nb * 8192);
            bf16x8 afrag[4];
#pragma unroll
            for (int mb = 0; mb < 4; ++mb)
                afrag[mb] = *(const bf16x8*)&lsA[(mb * 16 + col) * 8 + ((kkc + quad) ^ cw)];
#pragma unroll
            for (int nb = 0; nb < 4; ++nb)
#pragma unroll
                for (int mb = 0; mb < 4; ++mb)
                    acc[mb][nb] = __builtin_amdgcn_mfma_f32_16x16x32_bf16(afrag[mb], bfrag[nb], acc[mb][nb], 0, 0, 0);
        }
        a0 = n0; a1 = n1; a2 = n2; a3 = n3;
    }

    // epilogue: partial sum over this block's 256 units of v*tanh(relu(acc+b1)+hp)
    // tanh(x) = 1 - 2/(exp(2x)+1)
    float b1v[4], hpv[4], vv[4];
    float sumv = 0.f;
    int uB = half * 256 + wave * 64 + col;
#pragma unroll
    for (int nb = 0; nb < 4; ++nb) {
        int u = uB + nb * 16;
        b1v[nb] = b1[u];
        hpv[nb] = hp[(size_t)b * 512 + u];
        vv[nb] = Vw[u];
        sumv += vv[nb];
    }
#pragma unroll
    for (int mb = 0; mb < 4; ++mb) {
#pragma unroll
        for (int r = 0; r < 4; ++r) {
            float p2 = 0.f;
#pragma unroll
            for (int nb = 0; nb < 4; ++nb) {
                float x = fmaxf(acc[mb][nb][r] + b1v[nb], 0.f) + hpv[nb];
                float e = __builtin_amdgcn_exp2f(x * 2.885390082f);   // exp(2x)
                float rc = __builtin_amdgcn_rcpf(e + 1.0f);
                p2 += vv[nb] * rc;
            }
            float p = sumv - 2.0f * p2;   // sum_nb v*(1-2/(e+1))
            p += __shfl_xor(p, 1);
            p += __shfl_xor(p, 2);
            p += __shfl_xor(p, 4);
            p += __shfl_xor(p, 8);
            if (col == 0) lds_part[wave][mb * 16 + quad * 4 + r] = p;
        }
    }
    __syncthreads();
    if (t < MT) {
        float s = lds_part[0][t] + lds_part[1][t] + lds_part[2][t] + lds_part[3][t];
        int sg = s0 + t;
        if (sg < 360)
            scoresP[(size_t)half * BS * SEQ + (size_t)b * SEQ + sg] = s;
    }
}

// ---------------- Kernel 3: softmax + context (4 emb-chunks per batch) ----------------
__global__ __launch_bounds__(256) void k_softctx(const float* __restrict__ F,
                                                 const float* __restrict__ scoresP,
                                                 float* __restrict__ outc,
                                                 float* __restrict__ outw) {
    __shared__ float wL[SEQ];
    __shared__ float red[8];
    __shared__ f32x4 red8[8][32];
    int t = threadIdx.x;
    int b = blockIdx.x >> 2;
    int chunk = blockIdx.x & 3;
    int lane = t & 63, wid = t >> 6;

    const float* sp0 = scoresP + (size_t)b * SEQ;
    const float* sp1 = scoresP + (size_t)BS * SEQ + (size_t)b * SEQ;
    float sa = (t < SEQ) ? (sp0[t] + sp1[t]) : -1e30f;
    float sb = (t + 256 < SEQ) ? (sp0[t + 256] + sp1[t + 256]) : -1e30f;
    float m = fmaxf(sa, sb);
#pragma unroll
    for (int off = 32; off; off >>= 1) m = fmaxf(m, __shfl_xor(m, off));
    if (lane == 0) red[wid] = m;
    __syncthreads();
    m = fmaxf(fmaxf(red[0], red[1]), fmaxf(red[2], red[3]));

    const float L2E = 1.4426950408889634f;
    float e0 = (t < SEQ) ? __builtin_amdgcn_exp2f((sa - m) * L2E) : 0.f;
    float e1 = (t + 256 < SEQ) ? __builtin_amdgcn_exp2f((sb - m) * L2E) : 0.f;
    float sum = e0 + e1;
#pragma unroll
    for (int off = 32; off; off >>= 1) sum += __shfl_xor(sum, off);
    if (lane == 0) red[4 + wid] = sum;
    __syncthreads();
    float inv = 1.0f / (red[4] + red[5] + red[6] + red[7]);

    if (t < SEQ) {
        float w = e0 * inv;
        wL[t] = w;
        if (chunk == 0) outw[(size_t)b * SEQ + t] = w;
    }
    if (t + 256 < SEQ) {
        float w = e1 * inv;
        wL[t + 256] = w;
        if (chunk == 0) outw[(size_t)b * SEQ + t + 256] = w;
    }
    __syncthreads();

    // context chunk: 128 floats = 32 f32x4 lanes x 8 s-strips
    int c4 = t & 31, strip = t >> 5;
    const f32x4* Fb = (const f32x4*)F + (size_t)b * SEQ * 128 + chunk * 32 + c4;
    f32x4 a = {0.f, 0.f, 0.f, 0.f};
    for (int s = strip; s < SEQ; s += 8) a += wL[s] * Fb[(size_t)s * 128];
    red8[strip][c4] = a;
    __syncthreads();
    if (t < 32) {
        f32x4 s = red8[0][t];
#pragma unroll
        for (int k = 1; k < 8; ++k) s += red8[k][t];
        ((f32x4*)outc)[(size_t)b * 128 + chunk * 32 + t] = s;
    }
}

// ---------------- Launch ----------------
extern "C" void kernel_launch(void* const* d_in, const int* in_sizes, int n_in,
                              void* d_out, int out_size, void* d_ws, size_t ws_size,
                              hipStream_t stream) {
    const float* hidden   = (const float*)d_in[0];
    const float* features = (const float*)d_in[1];
    const float* W1_w     = (const float*)d_in[2];
    const float* W1_b     = (const float*)d_in[3];
    const float* W2_w     = (const float*)d_in[4];
    const float* W2_b     = (const float*)d_in[5];
    const float* V_w      = (const float*)d_in[6];
    // V_b unused: constant shift cancels in softmax.

    float* outc = (float*)d_out;                    // [1024, 512]
    float* outw = (float*)d_out + (size_t)BS * EMB; // [1024, 360]

    char* ws = (char*)d_ws;
    unsigned short* w1p = (unsigned short*)ws;                  // 512 KB packed W1
    float* hp      = (float*)(ws + 524288);                     // 2 MB
    float* scoresP = (float*)(ws + 524288 + 2097152);           // 2 x 1.44 MB partials

    hipLaunchKernelGGL(k_convert_w1, dim3(128), dim3(256), 0, stream, W1_w, w1p);
    hipLaunchKernelGGL(k_hproj, dim3(256), dim3(256), 0, stream, hidden, W2_w, W2_b, hp);
    hipLaunchKernelGGL(k_score, dim3(BS * 12), dim3(256), 0, stream,
                       features, w1p, W1_b, hp, V_w, scoresP);
    hipLaunchKernelGGL(k_softctx, dim3(BS * 4), dim3(256), 0, stream,
                       features, scoresP, outc, outw);
}